// Round 3
// baseline (161.946 us; speedup 1.0000x reference)
//
#include <hip/hip_runtime.h>
#include <hip/hip_bf16.h>
#include <cstdint>
#include <cstddef>

// PointAttention: out = concat( diag_softmax(eps_mlp((q_i - k_j + pij)*s)) * v , features )
// Folding: AE=s*A2@E1, BE=s*B2@E1, G=s*D2@E1, c0=s*(ab2-bb2+db2)@E1+eb1 (folded into qe); eb2 drops out.
// Softmax: logits are O(1) (scale applied pre-MLP) -> no max-subtraction needed (f32 exp safe).

#define SCALE 0.08838834764831843f

typedef __bf16 bf16x8 __attribute__((ext_vector_type(8)));
typedef float f32x16 __attribute__((ext_vector_type(16)));

__device__ __forceinline__ ushort f2b(float f){
  __hip_bfloat16 h = __float2bfloat16(f);
  return __builtin_bit_cast(ushort, h);
}
__device__ __forceinline__ float b2f(uint32_t s){
  union { uint32_t u; float f; } x; x.u = s << 16; return x.f;
}
__device__ __forceinline__ float blo(uint32_t u){
  union { uint32_t x; float f; } v; v.x = u << 16; return v.f;
}
__device__ __forceinline__ float bhi(uint32_t u){
  union { uint32_t x; float f; } v; v.x = u & 0xffff0000u; return v.f;
}
__device__ __forceinline__ uint32_t pk2(float a, float b){
  union { __hip_bfloat162 h2; uint32_t u; } x;
  x.h2.x = __float2bfloat16(a); x.h2.y = __float2bfloat16(b);
  return x.u;
}
__device__ __forceinline__ f32x16 MFMA(uint4 a, uint4 b, f32x16 c){
  return __builtin_amdgcn_mfma_f32_32x32x16_bf16(
      __builtin_bit_cast(bf16x8, a), __builtin_bit_cast(bf16x8, b), c, 0, 0, 0);
}

// ---------------- Kernel P: weight folding + panelization ----------------
// panel[k_oct][x][e] = Mat[8*k_oct+e][x]  (bf16, conflict-free for frag ds_read_b128)
__global__ __launch_bounds__(256) void k_pre(
    const float* __restrict__ A2, const float* __restrict__ B2, const float* __restrict__ D2,
    const float* __restrict__ E1, const float* __restrict__ E2,
    const float* __restrict__ O1, const float* __restrict__ O2,
    const float* __restrict__ ab2, const float* __restrict__ bb2, const float* __restrict__ db2,
    const float* __restrict__ eb1,
    const float* __restrict__ D1, const float* __restrict__ db1,
    ushort* __restrict__ aep, ushort* __restrict__ bep, ushort* __restrict__ gtp,
    ushort* __restrict__ e2p, ushort* __restrict__ o2p, ushort* __restrict__ o1t,
    ushort* __restrict__ d1p, float* __restrict__ c0)
{
  const int bid = blockIdx.x, tid = threadIdx.x;
  if (bid < 192){                 // AE / BE / G = s*(W @ E1), panelized
    const float* W = (bid < 64) ? A2 : (bid < 128) ? B2 : D2;
    ushort* dst    = (bid < 64) ? aep : (bid < 128) ? bep : gtp;
    int flat = (bid & 63)*256 + tid;
    int co = flat >> 10, rem = flat & 1023, h = rem >> 3, i = rem & 7;
    int r = co*8 + i;
    float acc = 0.f;
    for (int t = 0; t < 128; ++t) acc = fmaf(W[r*128 + t], E1[t*128 + h], acc);
    dst[(co*128 + h)*8 + i] = f2b(acc * SCALE);
  } else if (bid < 256){          // E2 panel
    int flat = (bid - 192)*256 + tid;
    int co = flat >> 10, rem = flat & 1023, d = rem >> 3, i = rem & 7;
    e2p[(co*128 + d)*8 + i] = f2b(E2[(co*8 + i)*128 + d]);
  } else if (bid < 320){          // O2 panel
    int flat = (bid - 256)*256 + tid;
    int co = flat >> 10, rem = flat & 1023, d = rem >> 3, i = rem & 7;
    o2p[(co*128 + d)*8 + i] = f2b(O2[(co*8 + i)*128 + d]);
  } else if (bid < 352){          // O1^T panel (A-operand: rows=o, k=f)
    int flat = (bid - 320)*256 + tid;   // 8192 elems
    int fo = flat >> 10, rem = flat & 1023, o = rem >> 3, e = rem & 7;
    o1t[(fo*128 + o)*8 + e] = f2b(O1[(fo*8 + e)*128 + o]);
  } else if (bid < 360){          // D1 A-frag panel: [2 koct][128 cd][8]
    int flat = (bid - 352)*256 + tid;   // 2048 elems
    int koct = flat >> 10, cd = (flat >> 3) & 127, e = flat & 7;
    float val = 0.f;
    if (koct == 0){
      if (e < 3) val = D1[e*128 + cd];
      else if (e == 3) val = db1[cd];
    }
    d1p[flat] = f2b(val);
  } else {
    if (tid < 128){
      float acc = 0.f;
      for (int t = 0; t < 128; ++t) acc = fmaf(ab2[t] - bb2[t] + db2[t], E1[t*128 + tid], acc);
      c0[tid] = acc * SCALE + eb1[tid];
    }
  }
}

// ---------------- Kernel Q: per-point qe/ke/v + features passthrough ----------------
__device__ __forceinline__ void gemm64x128(const ushort (*sa)[64][8], const ushort (*sw)[128][8],
                                           int w, int l31, int hl, int p0,
                                           const float* __restrict__ bias,
                                           ushort* __restrict__ dst)
{
  const int rw = w >> 1, ctb = (w & 1) * 2;
  f32x16 acc0, acc1;
#pragma unroll
  for (int r = 0; r < 16; ++r){ acc0[r] = 0.f; acc1[r] = 0.f; }
#pragma unroll
  for (int kk = 0; kk < 8; ++kk){
    uint4 a  = *(const uint4*)&sa[2*kk + hl][32*rw + l31][0];
    uint4 b0 = *(const uint4*)&sw[2*kk + hl][32*ctb + l31][0];
    uint4 b1 = *(const uint4*)&sw[2*kk + hl][32*(ctb+1) + l31][0];
    acc0 = MFMA(a, b0, acc0);
    acc1 = MFMA(a, b1, acc1);
  }
#pragma unroll
  for (int t = 0; t < 2; ++t){
    const f32x16 acc = t ? acc1 : acc0;
    const int d = 32*(ctb + t) + l31;
    const float bv = bias ? bias[d] : 0.f;
#pragma unroll
    for (int r = 0; r < 16; ++r){
      int row = 32*rw + (r & 3) + 8*(r >> 2) + 4*hl;
      dst[(size_t)(p0 + row)*128 + d] = f2b(acc[r] + bv);
    }
  }
}

__global__ __launch_bounds__(256, 2) void k_point(
    const float* __restrict__ pv, const float* __restrict__ feat,
    const float* __restrict__ A1, const float* __restrict__ ab1,
    const float* __restrict__ B1, const float* __restrict__ bb1,
    const float* __restrict__ ob1, const float* __restrict__ ob2,
    const float* __restrict__ c0,
    const uint4* __restrict__ aep, const uint4* __restrict__ bep,
    const uint4* __restrict__ o1t, const uint4* __restrict__ o2p,
    ushort* __restrict__ qe_ws, ushort* __restrict__ ke_ws, ushort* __restrict__ v_ws,
    float* __restrict__ out)
{
  __shared__ ushort sW[16][128][8];   // 32 KB weight panel
  __shared__ ushort sA[16][64][8];    // 16 KB activation panel
  __shared__ ushort sF[8][64][8];     // 8 KB  feature panel
  __shared__ float  sLw[3][128];
  __shared__ float  sLb[128];
  __shared__ float  sLb2[128];

  const int tid = threadIdx.x;
  const int p0  = blockIdx.x * 64;
  const int w = tid >> 6, lane = tid & 63, l31 = lane & 31, hl = lane >> 5;

  // exact f32 features passthrough: out[:,:,128:192]
  for (int idx = tid; idx < 64*16; idx += 256){
    int p = idx >> 4, k4 = idx & 15;
    float4 f = ((const float4*)(feat + (size_t)(p0 + p)*64))[k4];
    ((float4*)(out + (size_t)(p0 + p)*192 + 128))[k4] = f;
  }

  // ---- phase A: ha = relu(xyz@A1+ab1); qe = ha@AE + c0 ----
  for (int idx = tid; idx < 2048; idx += 256) ((uint4*)sW)[idx] = aep[idx];
  for (int idx = tid; idx < 384; idx += 256) ((float*)sLw)[idx] = A1[idx];
  if (tid < 128) sLb[tid] = ab1[tid];
  __syncthreads();
  {
    int p = tid & 63, ob = tid >> 6;
    float x0 = pv[(size_t)(p0+p)*3+0], x1 = pv[(size_t)(p0+p)*3+1], x2 = pv[(size_t)(p0+p)*3+2];
#pragma unroll
    for (int it = 0; it < 4; ++it){
      int oct = ob + 4*it;
      float h[8];
#pragma unroll
      for (int e = 0; e < 8; ++e){
        int cd = oct*8 + e;
        float t = fmaf(x0, sLw[0][cd], fmaf(x1, sLw[1][cd], fmaf(x2, sLw[2][cd], sLb[cd])));
        h[e] = fmaxf(t, 0.f);
      }
      uint4 u; u.x = pk2(h[0],h[1]); u.y = pk2(h[2],h[3]); u.z = pk2(h[4],h[5]); u.w = pk2(h[6],h[7]);
      *(uint4*)&sA[oct][p][0] = u;
    }
  }
  __syncthreads();
  gemm64x128(sA, sW, w, l31, hl, p0, c0, qe_ws);
  __syncthreads();

  // ---- phase B: ke = hb@BE ----
  for (int idx = tid; idx < 2048; idx += 256) ((uint4*)sW)[idx] = bep[idx];
  for (int idx = tid; idx < 384; idx += 256) ((float*)sLw)[idx] = B1[idx];
  if (tid < 128) sLb[tid] = bb1[tid];
  __syncthreads();
  {
    int p = tid & 63, ob = tid >> 6;
    float x0 = pv[(size_t)(p0+p)*3+0], x1 = pv[(size_t)(p0+p)*3+1], x2 = pv[(size_t)(p0+p)*3+2];
#pragma unroll
    for (int it = 0; it < 4; ++it){
      int oct = ob + 4*it;
      float h[8];
#pragma unroll
      for (int e = 0; e < 8; ++e){
        int cd = oct*8 + e;
        float t = fmaf(x0, sLw[0][cd], fmaf(x1, sLw[1][cd], fmaf(x2, sLw[2][cd], sLb[cd])));
        h[e] = fmaxf(t, 0.f);
      }
      uint4 u; u.x = pk2(h[0],h[1]); u.y = pk2(h[2],h[3]); u.z = pk2(h[4],h[5]); u.w = pk2(h[6],h[7]);
      *(uint4*)&sA[oct][p][0] = u;
    }
  }
  __syncthreads();
  gemm64x128(sA, sW, w, l31, hl, p0, nullptr, ke_ws);
  __syncthreads();

  // ---- phase C: ho^T = relu(O1^T @ feat^T + ob1) ----
  for (int idx = tid; idx < 512; idx += 256){
    int p = idx & 63, fo = idx >> 6;
    const float* fp = feat + (size_t)(p0 + p)*64 + 8*fo;
    float4 f0 = ((const float4*)fp)[0], f1 = ((const float4*)fp)[1];
    uint4 u; u.x = pk2(f0.x,f0.y); u.y = pk2(f0.z,f0.w); u.z = pk2(f1.x,f1.y); u.w = pk2(f1.z,f1.w);
    *(uint4*)&sF[fo][p][0] = u;
  }
  for (int idx = tid; idx < 1024; idx += 256) ((uint4*)sW)[idx] = o1t[idx];
  if (tid < 128) sLb[tid] = ob1[tid];
  __syncthreads();
  {
    f32x16 acc0, acc1;
#pragma unroll
    for (int r = 0; r < 16; ++r){ acc0[r] = 0.f; acc1[r] = 0.f; }
#pragma unroll
    for (int kk = 0; kk < 4; ++kk){
      uint4 a  = *(const uint4*)&sW[2*kk + hl][32*w + l31][0];
      uint4 b0 = *(const uint4*)&sF[2*kk + hl][l31][0];
      uint4 b1 = *(const uint4*)&sF[2*kk + hl][32 + l31][0];
      acc0 = MFMA(a, b0, acc0);
      acc1 = MFMA(a, b1, acc1);
    }
#pragma unroll
    for (int t = 0; t < 2; ++t){
      const f32x16 acc = t ? acc1 : acc0;
      const int pt = 32*t + l31;
#pragma unroll
      for (int q = 0; q < 4; ++q){
        int o0 = 32*w + 8*q + 4*hl;
        float z0 = fmaxf(acc[4*q+0] + sLb[o0+0], 0.f);
        float z1 = fmaxf(acc[4*q+1] + sLb[o0+1], 0.f);
        float z2 = fmaxf(acc[4*q+2] + sLb[o0+2], 0.f);
        float z3 = fmaxf(acc[4*q+3] + sLb[o0+3], 0.f);
        uint2 u; u.x = pk2(z0, z1); u.y = pk2(z2, z3);
        *(uint2*)&sA[4*w + q][pt][4*hl] = u;
      }
    }
  }
  __syncthreads();

  // ---- phase D: v = ho @ O2 + ob2 ----
  for (int idx = tid; idx < 2048; idx += 256) ((uint4*)sW)[idx] = o2p[idx];
  if (tid < 128) sLb2[tid] = ob2[tid];
  __syncthreads();
  {
    const int rw = w >> 1, ctb = (w & 1) * 2;
    f32x16 acc0, acc1;
#pragma unroll
    for (int r = 0; r < 16; ++r){ acc0[r] = 0.f; acc1[r] = 0.f; }
#pragma unroll
    for (int kk = 0; kk < 8; ++kk){
      uint4 a  = *(const uint4*)&sA[2*kk + hl][32*rw + l31][0];
      uint4 b0 = *(const uint4*)&sW[2*kk + hl][32*ctb + l31][0];
      uint4 b1 = *(const uint4*)&sW[2*kk + hl][32*(ctb+1) + l31][0];
      acc0 = MFMA(a, b0, acc0);
      acc1 = MFMA(a, b1, acc1);
    }
#pragma unroll
    for (int t = 0; t < 2; ++t){
      const f32x16 acc = t ? acc1 : acc0;
      const int d = 32*(ctb + t) + l31;
      const float bias = sLb2[d];
#pragma unroll
      for (int r = 0; r < 16; ++r){
        int row = 32*rw + (r & 3) + 8*(r >> 2) + 4*hl;
        v_ws[(size_t)(p0 + row)*128 + d] = f2b(acc[r] + bias);
      }
    }
  }
}

// ---------------- Kernel M: per-voxel attention core (half-voxel per block) ----------------
__global__ __launch_bounds__(256, 4) void k_main(
    const float* __restrict__ pv,
    const ushort* __restrict__ qe_ws, const ushort* __restrict__ ke_ws, const ushort* __restrict__ v_ws,
    const uint4* __restrict__ gtp, const uint4* __restrict__ e2p, const uint4* __restrict__ d1p,
    float* __restrict__ out)
{
  __shared__ ushort sHDE[16][128][8];  // 32 KB: HD panel, then HE panel (same buffer)
  __shared__ ushort sQE[16][128];      // 4 KB: qe (+c0) raw bf16 rows for this half-voxel
  __shared__ float  sXYZ[32][3];       // 384 B

  const int tid = threadIdx.x;
  const int b   = blockIdx.x >> 1;
  const int ch0 = (blockIdx.x & 1) * 4;   // chunks ch0..ch0+3 (rows i = 4*ch0 .. 4*ch0+15)
  const int w = tid >> 6, lane = tid & 63, l31 = lane & 31, hl = lane >> 5;

  for (int idx = tid; idx < 96; idx += 256) ((float*)sXYZ)[idx] = pv[(size_t)b*96 + idx];
  // raw bf16 copy of this half-voxel's 16 qe rows (c0 already folded in k_point)
  for (int idx = tid; idx < 512; idx += 256)
    ((uint2*)sQE)[idx] = ((const uint2*)qe_ws)[(size_t)(b*32 + 4*ch0)*32 + idx];

  // per-thread constants: ke[j=l31][h-slice] (16 f32), weight fragments
  float kreg[16];
  {
    const ushort* kp = ke_ws + (size_t)(b*32 + l31)*128 + 32*w + 4*hl;
#pragma unroll
    for (int q = 0; q < 4; ++q){
      uint2 ku = *(const uint2*)(kp + 8*q);
      kreg[4*q+0] = b2f(ku.x & 0xffff); kreg[4*q+1] = b2f(ku.x >> 16);
      kreg[4*q+2] = b2f(ku.y & 0xffff); kreg[4*q+3] = b2f(ku.y >> 16);
    }
  }
  uint4 wG[8], wE[8];
#pragma unroll
  for (int kk = 0; kk < 8; ++kk){
    wG[kk] = gtp[(2*kk + hl)*128 + 32*w + l31];  // A-frag rows h = 32w..32w+31
    wE[kk] = e2p[(2*kk + hl)*128 + 32*w + l31];  // B-frag cols d = 32w..32w+31
  }
  uint4 wD = d1p[hl*128 + 32*w + l31];           // A-frag rows cd = 32w..32w+31, K=4 padded
  __syncthreads();

  const float xj0 = sXYZ[l31][0], xj1 = sXYZ[l31][1], xj2 = sXYZ[l31][2];

#pragma unroll
  for (int cc = 0; cc < 4; ++cc){
    const int c = ch0 + cc;

    // ---- HD via MFMA: HD^T[cd][p] = relu([D1;db1]^T @ [dxyz;1]) ----
    f32x16 accD[4];
#pragma unroll
    for (int ct = 0; ct < 4; ++ct){
      const int i = 4*c + ct;
      float dx = fabsf(sXYZ[i][0] - xj0);
      float dy = fabsf(sXYZ[i][1] - xj1);
      float dz = fabsf(sXYZ[i][2] - xj2);
      uint4 bD; bD.x = pk2(dx, dy); bD.y = pk2(dz, 1.0f); bD.z = 0u; bD.w = 0u;
      f32x16 z;
#pragma unroll
      for (int r = 0; r < 16; ++r) z[r] = 0.f;
      accD[ct] = MFMA(wD, bD, z);
    }
#pragma unroll
    for (int ct = 0; ct < 4; ++ct){
#pragma unroll
      for (int q = 0; q < 4; ++q){
        uint2 o;
        o.x = pk2(fmaxf(accD[ct][4*q+0],0.f), fmaxf(accD[ct][4*q+1],0.f));
        o.y = pk2(fmaxf(accD[ct][4*q+2],0.f), fmaxf(accD[ct][4*q+3],0.f));
        *(uint2*)&sHDE[4*w + q][32*ct + l31][4*hl] = o;
      }
    }
    __syncthreads();

    // ---- GEMM1: HE^T[h][p] = G^T @ HD^T, C-in = qe_i(+c0) - ke_j ----
    f32x16 acc1[4];
#pragma unroll
    for (int ct = 0; ct < 4; ++ct){
      const int il = 4*cc + ct;
#pragma unroll
      for (int q = 0; q < 4; ++q){
        uint2 qu = *(const uint2*)&sQE[il][32*w + 4*hl + 8*q];
        acc1[ct][4*q+0] = blo(qu.x) - kreg[4*q+0];
        acc1[ct][4*q+1] = bhi(qu.x) - kreg[4*q+1];
        acc1[ct][4*q+2] = blo(qu.y) - kreg[4*q+2];
        acc1[ct][4*q+3] = bhi(qu.y) - kreg[4*q+3];
      }
    }
#pragma unroll
    for (int kk = 0; kk < 8; ++kk){
      uint4 a = wG[kk];
#pragma unroll
      for (int ct = 0; ct < 4; ++ct){
        uint4 bu = *(const uint4*)&sHDE[2*kk + hl][32*ct + l31][0];
        acc1[ct] = MFMA(a, bu, acc1[ct]);
      }
    }
    __syncthreads();   // done reading HD panel

    // ---- relu -> HE panel (overwrite same LDS) ----
#pragma unroll
    for (int ct = 0; ct < 4; ++ct){
#pragma unroll
      for (int q = 0; q < 4; ++q){
        uint2 o;
        o.x = pk2(fmaxf(acc1[ct][4*q+0],0.f), fmaxf(acc1[ct][4*q+1],0.f));
        o.y = pk2(fmaxf(acc1[ct][4*q+2],0.f), fmaxf(acc1[ct][4*q+3],0.f));
        *(uint2*)&sHDE[4*w + q][32*ct + l31][4*hl] = o;
      }
    }
    __syncthreads();

    // ---- v prefetch (hides under GEMM2) ----
    float vv[4];
#pragma unroll
    for (int rt = 0; rt < 4; ++rt)
      vv[rt] = b2f((uint32_t)v_ws[(size_t)(b*32 + 4*c + rt)*128 + 32*w + l31]);

    // ---- GEMM2: W[j][d] = HE @ E2 (eb2 softmax-invariant) ----
    f32x16 acc2[4];
#pragma unroll
    for (int rt = 0; rt < 4; ++rt)
#pragma unroll
      for (int r = 0; r < 16; ++r) acc2[rt][r] = 0.f;
#pragma unroll
    for (int kk = 0; kk < 8; ++kk){
      uint4 bfrag = wE[kk];
#pragma unroll
      for (int rt = 0; rt < 4; ++rt){
        uint4 au = *(const uint4*)&sHDE[2*kk + hl][32*rt + l31][0];
        acc2[rt] = MFMA(au, bfrag, acc2[rt]);
      }
    }

    // ---- softmax over j per (i,d), no max-sub (logits O(1)); diag numerator; res = wii*v ----
    const int g = (c >> 1) & 3;     // diag register group (static-index select)
    const int hls = c & 1;          // diag hl half
#pragma unroll
    for (int rt = 0; rt < 4; ++rt){
      float e[16];
#pragma unroll
      for (int r = 0; r < 16; ++r) e[r] = __expf(acc2[rt][r]);
      float s01 = e[0]+e[1],   s23 = e[2]+e[3],   s45 = e[4]+e[5],   s67 = e[6]+e[7];
      float s89 = e[8]+e[9],   sab = e[10]+e[11], scd = e[12]+e[13], sef = e[14]+e[15];
      float s = ((s01+s23)+(s45+s67)) + ((s89+sab)+(scd+sef));
      s += __shfl_xor(s, 32);
      float num = (g == 0) ? e[rt] : (g == 1) ? e[rt+4] : (g == 2) ? e[rt+8] : e[rt+12];
      if (hl == hls){
        out[(size_t)(b*32 + 4*c + rt)*192 + 32*w + l31] = num * __builtin_amdgcn_rcpf(s) * vv[rt];
      }
    }
    __syncthreads();   // protect HE panel before next chunk's HD write
  }
}

// ---------------- launch ----------------
static constexpr size_t OFF_AEP = 0;
static constexpr size_t OFF_BEP = 32768;
static constexpr size_t OFF_GTP = 65536;
static constexpr size_t OFF_E2P = 98304;
static constexpr size_t OFF_O1T = 131072;
static constexpr size_t OFF_O2P = 147456;
static constexpr size_t OFF_C0  = 180224;
static constexpr size_t OFF_D1P = 180736;
static constexpr size_t OFF_QE  = 184832;
static constexpr size_t OFF_KE  = OFF_QE + (size_t)32768*128*2;
static constexpr size_t OFF_V   = OFF_KE + (size_t)32768*128*2;

extern "C" void kernel_launch(void* const* d_in, const int* in_sizes, int n_in,
                              void* d_out, int out_size, void* d_ws, size_t ws_size,
                              hipStream_t stream)
{
  (void)in_sizes; (void)n_in; (void)out_size; (void)ws_size;
  const float* pv   = (const float*)d_in[0];
  const float* feat = (const float*)d_in[1];
  const float* A1 = (const float*)d_in[2];  const float* ab1 = (const float*)d_in[3];
  const float* A2 = (const float*)d_in[4];  const float* ab2 = (const float*)d_in[5];
  const float* B1 = (const float*)d_in[6];  const float* bb1 = (const float*)d_in[7];
  const float* B2 = (const float*)d_in[8];  const float* bb2 = (const float*)d_in[9];
  const float* D1 = (const float*)d_in[10]; const float* db1 = (const float*)d_in[11];
  const float* D2 = (const float*)d_in[12]; const float* db2 = (const float*)d_in[13];
  const float* E1 = (const float*)d_in[14]; const float* eb1 = (const float*)d_in[15];
  const float* E2 = (const float*)d_in[16]; /* d_in[17] = eb2 unused (softmax-invariant) */
  const float* O1 = (const float*)d_in[18]; const float* ob1 = (const float*)d_in[19];
  const float* O2 = (const float*)d_in[20]; const float* ob2 = (const float*)d_in[21];

  char* ws = (char*)d_ws;
  ushort* aep = (ushort*)(ws + OFF_AEP);
  ushort* bep = (ushort*)(ws + OFF_BEP);
  ushort* gtp = (ushort*)(ws + OFF_GTP);
  ushort* e2p = (ushort*)(ws + OFF_E2P);
  ushort* o1t = (ushort*)(ws + OFF_O1T);
  ushort* o2p = (ushort*)(ws + OFF_O2P);
  float*  c0  = (float*)(ws + OFF_C0);
  ushort* d1p = (ushort*)(ws + OFF_D1P);
  ushort* qe  = (ushort*)(ws + OFF_QE);
  ushort* ke  = (ushort*)(ws + OFF_KE);
  ushort* vv  = (ushort*)(ws + OFF_V);
  float* out = (float*)d_out;

  hipLaunchKernelGGL(k_pre, dim3(361), dim3(256), 0, stream,
                     A2, B2, D2, E1, E2, O1, O2, ab2, bb2, db2, eb1, D1, db1,
                     aep, bep, gtp, e2p, o2p, o1t, d1p, c0);
  hipLaunchKernelGGL(k_point, dim3(512), dim3(256), 0, stream,
                     pv, feat, A1, ab1, B1, bb1, ob1, ob2, c0,
                     (const uint4*)aep, (const uint4*)bep, (const uint4*)o1t, (const uint4*)o2p,
                     qe, ke, vv, out);
  hipLaunchKernelGGL(k_main, dim3(2048), dim3(256), 0, stream,
                     pv, qe, ke, vv, (const uint4*)gtp, (const uint4*)e2p, (const uint4*)d1p,
                     out);
}

// Round 4
// 120.222 us; speedup vs baseline: 1.3471x; 1.3471x over previous
//
#include <hip/hip_runtime.h>
#include <hip/hip_bf16.h>
#include <cstdint>
#include <cstddef>

// PointAttention: out = concat( diag_softmax(eps_mlp((q_i - k_j + pij)*s)) * v , features )
// Folding: AE=s*A2@E1, BE=s*B2@E1, G=s*D2@E1, c0=s*(ab2-bb2+db2)@E1+eb1 (folded into qe); eb2 drops out.
// Softmax: logits are O(1) (scale applied pre-MLP) -> no max-subtraction needed (f32 exp safe).
// NOTE: k_main needs ~150 live VGPRs (wG+wE+kreg+acc); launch_bounds(256,3) -> 170 cap, no spill.
//       (256,4) capped at 128 and spilled acc to scratch: FETCH 24->236MB, 115->141us. Do not re-try.

#define SCALE 0.08838834764831843f

typedef __bf16 bf16x8 __attribute__((ext_vector_type(8)));
typedef float f32x16 __attribute__((ext_vector_type(16)));

__device__ __forceinline__ ushort f2b(float f){
  __hip_bfloat16 h = __float2bfloat16(f);
  return __builtin_bit_cast(ushort, h);
}
__device__ __forceinline__ float b2f(uint32_t s){
  union { uint32_t u; float f; } x; x.u = s << 16; return x.f;
}
__device__ __forceinline__ float blo(uint32_t u){
  union { uint32_t x; float f; } v; v.x = u << 16; return v.f;
}
__device__ __forceinline__ float bhi(uint32_t u){
  union { uint32_t x; float f; } v; v.x = u & 0xffff0000u; return v.f;
}
__device__ __forceinline__ uint32_t pk2(float a, float b){
  union { __hip_bfloat162 h2; uint32_t u; } x;
  x.h2.x = __float2bfloat16(a); x.h2.y = __float2bfloat16(b);
  return x.u;
}
__device__ __forceinline__ f32x16 MFMA(uint4 a, uint4 b, f32x16 c){
  return __builtin_amdgcn_mfma_f32_32x32x16_bf16(
      __builtin_bit_cast(bf16x8, a), __builtin_bit_cast(bf16x8, b), c, 0, 0, 0);
}

// ---------------- Kernel P: weight folding + panelization ----------------
// panel[k_oct][x][e] = Mat[8*k_oct+e][x]  (bf16, conflict-free for frag ds_read_b128)
__global__ __launch_bounds__(256) void k_pre(
    const float* __restrict__ A2, const float* __restrict__ B2, const float* __restrict__ D2,
    const float* __restrict__ E1, const float* __restrict__ E2,
    const float* __restrict__ O1, const float* __restrict__ O2,
    const float* __restrict__ ab2, const float* __restrict__ bb2, const float* __restrict__ db2,
    const float* __restrict__ eb1,
    const float* __restrict__ D1, const float* __restrict__ db1,
    ushort* __restrict__ aep, ushort* __restrict__ bep, ushort* __restrict__ gtp,
    ushort* __restrict__ e2p, ushort* __restrict__ o2p, ushort* __restrict__ o1t,
    ushort* __restrict__ d1p, float* __restrict__ c0)
{
  const int bid = blockIdx.x, tid = threadIdx.x;
  if (bid < 192){                 // AE / BE / G = s*(W @ E1), panelized
    const float* W = (bid < 64) ? A2 : (bid < 128) ? B2 : D2;
    ushort* dst    = (bid < 64) ? aep : (bid < 128) ? bep : gtp;
    int flat = (bid & 63)*256 + tid;
    int co = flat >> 10, rem = flat & 1023, h = rem >> 3, i = rem & 7;
    int r = co*8 + i;
    float acc = 0.f;
    for (int t = 0; t < 128; ++t) acc = fmaf(W[r*128 + t], E1[t*128 + h], acc);
    dst[(co*128 + h)*8 + i] = f2b(acc * SCALE);
  } else if (bid < 256){          // E2 panel
    int flat = (bid - 192)*256 + tid;
    int co = flat >> 10, rem = flat & 1023, d = rem >> 3, i = rem & 7;
    e2p[(co*128 + d)*8 + i] = f2b(E2[(co*8 + i)*128 + d]);
  } else if (bid < 320){          // O2 panel
    int flat = (bid - 256)*256 + tid;
    int co = flat >> 10, rem = flat & 1023, d = rem >> 3, i = rem & 7;
    o2p[(co*128 + d)*8 + i] = f2b(O2[(co*8 + i)*128 + d]);
  } else if (bid < 352){          // O1^T panel (A-operand: rows=o, k=f)
    int flat = (bid - 320)*256 + tid;   // 8192 elems
    int fo = flat >> 10, rem = flat & 1023, o = rem >> 3, e = rem & 7;
    o1t[(fo*128 + o)*8 + e] = f2b(O1[(fo*8 + e)*128 + o]);
  } else if (bid < 360){          // D1 A-frag panel: [2 koct][128 cd][8]
    int flat = (bid - 352)*256 + tid;   // 2048 elems
    int koct = flat >> 10, cd = (flat >> 3) & 127, e = flat & 7;
    float val = 0.f;
    if (koct == 0){
      if (e < 3) val = D1[e*128 + cd];
      else if (e == 3) val = db1[cd];
    }
    d1p[flat] = f2b(val);
  } else {
    if (tid < 128){
      float acc = 0.f;
      for (int t = 0; t < 128; ++t) acc = fmaf(ab2[t] - bb2[t] + db2[t], E1[t*128 + tid], acc);
      c0[tid] = acc * SCALE + eb1[tid];
    }
  }
}

// ---------------- Kernel Q: per-point qe/ke/v + features passthrough ----------------
__device__ __forceinline__ void gemm64x128(const ushort (*sa)[64][8], const ushort (*sw)[128][8],
                                           int w, int l31, int hl, int p0,
                                           const float* __restrict__ bias,
                                           ushort* __restrict__ dst)
{
  const int rw = w >> 1, ctb = (w & 1) * 2;
  f32x16 acc0, acc1;
#pragma unroll
  for (int r = 0; r < 16; ++r){ acc0[r] = 0.f; acc1[r] = 0.f; }
#pragma unroll
  for (int kk = 0; kk < 8; ++kk){
    uint4 a  = *(const uint4*)&sa[2*kk + hl][32*rw + l31][0];
    uint4 b0 = *(const uint4*)&sw[2*kk + hl][32*ctb + l31][0];
    uint4 b1 = *(const uint4*)&sw[2*kk + hl][32*(ctb+1) + l31][0];
    acc0 = MFMA(a, b0, acc0);
    acc1 = MFMA(a, b1, acc1);
  }
#pragma unroll
  for (int t = 0; t < 2; ++t){
    const f32x16 acc = t ? acc1 : acc0;
    const int d = 32*(ctb + t) + l31;
    const float bv = bias ? bias[d] : 0.f;
#pragma unroll
    for (int r = 0; r < 16; ++r){
      int row = 32*rw + (r & 3) + 8*(r >> 2) + 4*hl;
      dst[(size_t)(p0 + row)*128 + d] = f2b(acc[r] + bv);
    }
  }
}

__global__ __launch_bounds__(256, 2) void k_point(
    const float* __restrict__ pv, const float* __restrict__ feat,
    const float* __restrict__ A1, const float* __restrict__ ab1,
    const float* __restrict__ B1, const float* __restrict__ bb1,
    const float* __restrict__ ob1, const float* __restrict__ ob2,
    const float* __restrict__ c0,
    const uint4* __restrict__ aep, const uint4* __restrict__ bep,
    const uint4* __restrict__ o1t, const uint4* __restrict__ o2p,
    ushort* __restrict__ qe_ws, ushort* __restrict__ ke_ws, ushort* __restrict__ v_ws,
    float* __restrict__ out)
{
  __shared__ ushort sW[16][128][8];   // 32 KB weight panel
  __shared__ ushort sA[16][64][8];    // 16 KB activation panel
  __shared__ ushort sF[8][64][8];     // 8 KB  feature panel
  __shared__ float  sLw[3][128];
  __shared__ float  sLb[128];
  __shared__ float  sLb2[128];

  const int tid = threadIdx.x;
  const int p0  = blockIdx.x * 64;
  const int w = tid >> 6, lane = tid & 63, l31 = lane & 31, hl = lane >> 5;

  // exact f32 features passthrough: out[:,:,128:192]
  for (int idx = tid; idx < 64*16; idx += 256){
    int p = idx >> 4, k4 = idx & 15;
    float4 f = ((const float4*)(feat + (size_t)(p0 + p)*64))[k4];
    ((float4*)(out + (size_t)(p0 + p)*192 + 128))[k4] = f;
  }

  // ---- phase A: ha = relu(xyz@A1+ab1); qe = ha@AE + c0 ----
  for (int idx = tid; idx < 2048; idx += 256) ((uint4*)sW)[idx] = aep[idx];
  for (int idx = tid; idx < 384; idx += 256) ((float*)sLw)[idx] = A1[idx];
  if (tid < 128) sLb[tid] = ab1[tid];
  __syncthreads();
  {
    int p = tid & 63, ob = tid >> 6;
    float x0 = pv[(size_t)(p0+p)*3+0], x1 = pv[(size_t)(p0+p)*3+1], x2 = pv[(size_t)(p0+p)*3+2];
#pragma unroll
    for (int it = 0; it < 4; ++it){
      int oct = ob + 4*it;
      float h[8];
#pragma unroll
      for (int e = 0; e < 8; ++e){
        int cd = oct*8 + e;
        float t = fmaf(x0, sLw[0][cd], fmaf(x1, sLw[1][cd], fmaf(x2, sLw[2][cd], sLb[cd])));
        h[e] = fmaxf(t, 0.f);
      }
      uint4 u; u.x = pk2(h[0],h[1]); u.y = pk2(h[2],h[3]); u.z = pk2(h[4],h[5]); u.w = pk2(h[6],h[7]);
      *(uint4*)&sA[oct][p][0] = u;
    }
  }
  __syncthreads();
  gemm64x128(sA, sW, w, l31, hl, p0, c0, qe_ws);
  __syncthreads();

  // ---- phase B: ke = hb@BE ----
  for (int idx = tid; idx < 2048; idx += 256) ((uint4*)sW)[idx] = bep[idx];
  for (int idx = tid; idx < 384; idx += 256) ((float*)sLw)[idx] = B1[idx];
  if (tid < 128) sLb[tid] = bb1[tid];
  __syncthreads();
  {
    int p = tid & 63, ob = tid >> 6;
    float x0 = pv[(size_t)(p0+p)*3+0], x1 = pv[(size_t)(p0+p)*3+1], x2 = pv[(size_t)(p0+p)*3+2];
#pragma unroll
    for (int it = 0; it < 4; ++it){
      int oct = ob + 4*it;
      float h[8];
#pragma unroll
      for (int e = 0; e < 8; ++e){
        int cd = oct*8 + e;
        float t = fmaf(x0, sLw[0][cd], fmaf(x1, sLw[1][cd], fmaf(x2, sLw[2][cd], sLb[cd])));
        h[e] = fmaxf(t, 0.f);
      }
      uint4 u; u.x = pk2(h[0],h[1]); u.y = pk2(h[2],h[3]); u.z = pk2(h[4],h[5]); u.w = pk2(h[6],h[7]);
      *(uint4*)&sA[oct][p][0] = u;
    }
  }
  __syncthreads();
  gemm64x128(sA, sW, w, l31, hl, p0, nullptr, ke_ws);
  __syncthreads();

  // ---- phase C: ho^T = relu(O1^T @ feat^T + ob1) ----
  for (int idx = tid; idx < 512; idx += 256){
    int p = idx & 63, fo = idx >> 6;
    const float* fp = feat + (size_t)(p0 + p)*64 + 8*fo;
    float4 f0 = ((const float4*)fp)[0], f1 = ((const float4*)fp)[1];
    uint4 u; u.x = pk2(f0.x,f0.y); u.y = pk2(f0.z,f0.w); u.z = pk2(f1.x,f1.y); u.w = pk2(f1.z,f1.w);
    *(uint4*)&sF[fo][p][0] = u;
  }
  for (int idx = tid; idx < 1024; idx += 256) ((uint4*)sW)[idx] = o1t[idx];
  if (tid < 128) sLb[tid] = ob1[tid];
  __syncthreads();
  {
    f32x16 acc0, acc1;
#pragma unroll
    for (int r = 0; r < 16; ++r){ acc0[r] = 0.f; acc1[r] = 0.f; }
#pragma unroll
    for (int kk = 0; kk < 4; ++kk){
      uint4 a  = *(const uint4*)&sW[2*kk + hl][32*w + l31][0];
      uint4 b0 = *(const uint4*)&sF[2*kk + hl][l31][0];
      uint4 b1 = *(const uint4*)&sF[2*kk + hl][32 + l31][0];
      acc0 = MFMA(a, b0, acc0);
      acc1 = MFMA(a, b1, acc1);
    }
#pragma unroll
    for (int t = 0; t < 2; ++t){
      const f32x16 acc = t ? acc1 : acc0;
      const int pt = 32*t + l31;
#pragma unroll
      for (int q = 0; q < 4; ++q){
        int o0 = 32*w + 8*q + 4*hl;
        float z0 = fmaxf(acc[4*q+0] + sLb[o0+0], 0.f);
        float z1 = fmaxf(acc[4*q+1] + sLb[o0+1], 0.f);
        float z2 = fmaxf(acc[4*q+2] + sLb[o0+2], 0.f);
        float z3 = fmaxf(acc[4*q+3] + sLb[o0+3], 0.f);
        uint2 u; u.x = pk2(z0, z1); u.y = pk2(z2, z3);
        *(uint2*)&sA[4*w + q][pt][4*hl] = u;
      }
    }
  }
  __syncthreads();

  // ---- phase D: v = ho @ O2 + ob2 ----
  for (int idx = tid; idx < 2048; idx += 256) ((uint4*)sW)[idx] = o2p[idx];
  if (tid < 128) sLb2[tid] = ob2[tid];
  __syncthreads();
  {
    const int rw = w >> 1, ctb = (w & 1) * 2;
    f32x16 acc0, acc1;
#pragma unroll
    for (int r = 0; r < 16; ++r){ acc0[r] = 0.f; acc1[r] = 0.f; }
#pragma unroll
    for (int kk = 0; kk < 8; ++kk){
      uint4 a  = *(const uint4*)&sA[2*kk + hl][32*rw + l31][0];
      uint4 b0 = *(const uint4*)&sW[2*kk + hl][32*ctb + l31][0];
      uint4 b1 = *(const uint4*)&sW[2*kk + hl][32*(ctb+1) + l31][0];
      acc0 = MFMA(a, b0, acc0);
      acc1 = MFMA(a, b1, acc1);
    }
#pragma unroll
    for (int t = 0; t < 2; ++t){
      const f32x16 acc = t ? acc1 : acc0;
      const int d = 32*(ctb + t) + l31;
      const float bias = sLb2[d];
#pragma unroll
      for (int r = 0; r < 16; ++r){
        int row = 32*rw + (r & 3) + 8*(r >> 2) + 4*hl;
        v_ws[(size_t)(p0 + row)*128 + d] = f2b(acc[r] + bias);
      }
    }
  }
}

// ---------------- Kernel M: per-voxel attention core (half-voxel per block) ----------------
__global__ __launch_bounds__(256, 3) void k_main(
    const float* __restrict__ pv,
    const ushort* __restrict__ qe_ws, const ushort* __restrict__ ke_ws, const ushort* __restrict__ v_ws,
    const uint4* __restrict__ gtp, const uint4* __restrict__ e2p, const uint4* __restrict__ d1p,
    float* __restrict__ out)
{
  __shared__ ushort sHDE[16][128][8];  // 32 KB: HD panel, then HE panel (same buffer)
  __shared__ ushort sQE[16][128];      // 4 KB: qe (+c0) raw bf16 rows for this half-voxel
  __shared__ float  sXYZ[32][3];       // 384 B

  const int tid = threadIdx.x;
  const int b   = blockIdx.x >> 1;
  const int ch0 = (blockIdx.x & 1) * 4;   // chunks ch0..ch0+3 (rows i = 4*ch0 .. 4*ch0+15)
  const int w = tid >> 6, lane = tid & 63, l31 = lane & 31, hl = lane >> 5;

  for (int idx = tid; idx < 96; idx += 256) ((float*)sXYZ)[idx] = pv[(size_t)b*96 + idx];
  // raw bf16 copy of this half-voxel's 16 qe rows (c0 already folded in k_point)
  for (int idx = tid; idx < 512; idx += 256)
    ((uint2*)sQE)[idx] = ((const uint2*)qe_ws)[(size_t)(b*32 + 4*ch0)*32 + idx];

  // per-thread constants: ke[j=l31][h-slice] (16 f32), weight fragments
  float kreg[16];
  {
    const ushort* kp = ke_ws + (size_t)(b*32 + l31)*128 + 32*w + 4*hl;
#pragma unroll
    for (int q = 0; q < 4; ++q){
      uint2 ku = *(const uint2*)(kp + 8*q);
      kreg[4*q+0] = b2f(ku.x & 0xffff); kreg[4*q+1] = b2f(ku.x >> 16);
      kreg[4*q+2] = b2f(ku.y & 0xffff); kreg[4*q+3] = b2f(ku.y >> 16);
    }
  }
  uint4 wG[8], wE[8];
#pragma unroll
  for (int kk = 0; kk < 8; ++kk){
    wG[kk] = gtp[(2*kk + hl)*128 + 32*w + l31];  // A-frag rows h = 32w..32w+31
    wE[kk] = e2p[(2*kk + hl)*128 + 32*w + l31];  // B-frag cols d = 32w..32w+31
  }
  uint4 wD = d1p[hl*128 + 32*w + l31];           // A-frag rows cd = 32w..32w+31, K=4 padded
  __syncthreads();

  const float xj0 = sXYZ[l31][0], xj1 = sXYZ[l31][1], xj2 = sXYZ[l31][2];

#pragma unroll
  for (int cc = 0; cc < 4; ++cc){
    const int c = ch0 + cc;

    // ---- HD via MFMA: HD^T[cd][p] = relu([D1;db1]^T @ [dxyz;1]) ----
    f32x16 accD[4];
#pragma unroll
    for (int ct = 0; ct < 4; ++ct){
      const int i = 4*c + ct;
      float dx = fabsf(sXYZ[i][0] - xj0);
      float dy = fabsf(sXYZ[i][1] - xj1);
      float dz = fabsf(sXYZ[i][2] - xj2);
      uint4 bD; bD.x = pk2(dx, dy); bD.y = pk2(dz, 1.0f); bD.z = 0u; bD.w = 0u;
      f32x16 z;
#pragma unroll
      for (int r = 0; r < 16; ++r) z[r] = 0.f;
      accD[ct] = MFMA(wD, bD, z);
    }
#pragma unroll
    for (int ct = 0; ct < 4; ++ct){
#pragma unroll
      for (int q = 0; q < 4; ++q){
        uint2 o;
        o.x = pk2(fmaxf(accD[ct][4*q+0],0.f), fmaxf(accD[ct][4*q+1],0.f));
        o.y = pk2(fmaxf(accD[ct][4*q+2],0.f), fmaxf(accD[ct][4*q+3],0.f));
        *(uint2*)&sHDE[4*w + q][32*ct + l31][4*hl] = o;
      }
    }
    __syncthreads();

    // ---- GEMM1: HE^T[h][p] = G^T @ HD^T, C-in = qe_i(+c0) - ke_j ----
    f32x16 acc1[4];
#pragma unroll
    for (int ct = 0; ct < 4; ++ct){
      const int il = 4*cc + ct;
#pragma unroll
      for (int q = 0; q < 4; ++q){
        uint2 qu = *(const uint2*)&sQE[il][32*w + 4*hl + 8*q];
        acc1[ct][4*q+0] = blo(qu.x) - kreg[4*q+0];
        acc1[ct][4*q+1] = bhi(qu.x) - kreg[4*q+1];
        acc1[ct][4*q+2] = blo(qu.y) - kreg[4*q+2];
        acc1[ct][4*q+3] = bhi(qu.y) - kreg[4*q+3];
      }
    }
#pragma unroll
    for (int kk = 0; kk < 8; ++kk){
      uint4 a = wG[kk];
#pragma unroll
      for (int ct = 0; ct < 4; ++ct){
        uint4 bu = *(const uint4*)&sHDE[2*kk + hl][32*ct + l31][0];
        acc1[ct] = MFMA(a, bu, acc1[ct]);
      }
    }
    __syncthreads();   // done reading HD panel

    // ---- relu -> HE panel (overwrite same LDS) ----
#pragma unroll
    for (int ct = 0; ct < 4; ++ct){
#pragma unroll
      for (int q = 0; q < 4; ++q){
        uint2 o;
        o.x = pk2(fmaxf(acc1[ct][4*q+0],0.f), fmaxf(acc1[ct][4*q+1],0.f));
        o.y = pk2(fmaxf(acc1[ct][4*q+2],0.f), fmaxf(acc1[ct][4*q+3],0.f));
        *(uint2*)&sHDE[4*w + q][32*ct + l31][4*hl] = o;
      }
    }
    __syncthreads();

    // ---- v prefetch (hides under GEMM2) ----
    float vv[4];
#pragma unroll
    for (int rt = 0; rt < 4; ++rt)
      vv[rt] = b2f((uint32_t)v_ws[(size_t)(b*32 + 4*c + rt)*128 + 32*w + l31]);

    // ---- GEMM2: W[j][d] = HE @ E2 (eb2 softmax-invariant) ----
    f32x16 acc2[4];
#pragma unroll
    for (int rt = 0; rt < 4; ++rt)
#pragma unroll
      for (int r = 0; r < 16; ++r) acc2[rt][r] = 0.f;
#pragma unroll
    for (int kk = 0; kk < 8; ++kk){
      uint4 bfrag = wE[kk];
#pragma unroll
      for (int rt = 0; rt < 4; ++rt){
        uint4 au = *(const uint4*)&sHDE[2*kk + hl][32*rt + l31][0];
        acc2[rt] = MFMA(au, bfrag, acc2[rt]);
      }
    }

    // ---- softmax over j per (i,d), no max-sub (logits O(1)); diag numerator; res = wii*v ----
    const int g = (c >> 1) & 3;     // diag register group (static-index select)
    const int hls = c & 1;          // diag hl half
#pragma unroll
    for (int rt = 0; rt < 4; ++rt){
      float e[16];
#pragma unroll
      for (int r = 0; r < 16; ++r) e[r] = __expf(acc2[rt][r]);
      float s01 = e[0]+e[1],   s23 = e[2]+e[3],   s45 = e[4]+e[5],   s67 = e[6]+e[7];
      float s89 = e[8]+e[9],   sab = e[10]+e[11], scd = e[12]+e[13], sef = e[14]+e[15];
      float s = ((s01+s23)+(s45+s67)) + ((s89+sab)+(scd+sef));
      s += __shfl_xor(s, 32);
      float num = (g == 0) ? e[rt] : (g == 1) ? e[rt+4] : (g == 2) ? e[rt+8] : e[rt+12];
      if (hl == hls){
        out[(size_t)(b*32 + 4*c + rt)*192 + 32*w + l31] = num * __builtin_amdgcn_rcpf(s) * vv[rt];
      }
    }
    __syncthreads();   // protect HE panel before next chunk's HD write
  }
}

// ---------------- launch ----------------
static constexpr size_t OFF_AEP = 0;
static constexpr size_t OFF_BEP = 32768;
static constexpr size_t OFF_GTP = 65536;
static constexpr size_t OFF_E2P = 98304;
static constexpr size_t OFF_O1T = 131072;
static constexpr size_t OFF_O2P = 147456;
static constexpr size_t OFF_C0  = 180224;
static constexpr size_t OFF_D1P = 180736;
static constexpr size_t OFF_QE  = 184832;
static constexpr size_t OFF_KE  = OFF_QE + (size_t)32768*128*2;
static constexpr size_t OFF_V   = OFF_KE + (size_t)32768*128*2;

extern "C" void kernel_launch(void* const* d_in, const int* in_sizes, int n_in,
                              void* d_out, int out_size, void* d_ws, size_t ws_size,
                              hipStream_t stream)
{
  (void)in_sizes; (void)n_in; (void)out_size; (void)ws_size;
  const float* pv   = (const float*)d_in[0];
  const float* feat = (const float*)d_in[1];
  const float* A1 = (const float*)d_in[2];  const float* ab1 = (const float*)d_in[3];
  const float* A2 = (const float*)d_in[4];  const float* ab2 = (const float*)d_in[5];
  const float* B1 = (const float*)d_in[6];  const float* bb1 = (const float*)d_in[7];
  const float* B2 = (const float*)d_in[8];  const float* bb2 = (const float*)d_in[9];
  const float* D1 = (const float*)d_in[10]; const float* db1 = (const float*)d_in[11];
  const float* D2 = (const float*)d_in[12]; const float* db2 = (const float*)d_in[13];
  const float* E1 = (const float*)d_in[14]; const float* eb1 = (const float*)d_in[15];
  const float* E2 = (const float*)d_in[16]; /* d_in[17] = eb2 unused (softmax-invariant) */
  const float* O1 = (const float*)d_in[18]; const float* ob1 = (const float*)d_in[19];
  const float* O2 = (const float*)d_in[20]; const float* ob2 = (const float*)d_in[21];

  char* ws = (char*)d_ws;
  ushort* aep = (ushort*)(ws + OFF_AEP);
  ushort* bep = (ushort*)(ws + OFF_BEP);
  ushort* gtp = (ushort*)(ws + OFF_GTP);
  ushort* e2p = (ushort*)(ws + OFF_E2P);
  ushort* o1t = (ushort*)(ws + OFF_O1T);
  ushort* o2p = (ushort*)(ws + OFF_O2P);
  float*  c0  = (float*)(ws + OFF_C0);
  ushort* d1p = (ushort*)(ws + OFF_D1P);
  ushort* qe  = (ushort*)(ws + OFF_QE);
  ushort* ke  = (ushort*)(ws + OFF_KE);
  ushort* vv  = (ushort*)(ws + OFF_V);
  float* out = (float*)d_out;

  hipLaunchKernelGGL(k_pre, dim3(361), dim3(256), 0, stream,
                     A2, B2, D2, E1, E2, O1, O2, ab2, bb2, db2, eb1, D1, db1,
                     aep, bep, gtp, e2p, o2p, o1t, d1p, c0);
  hipLaunchKernelGGL(k_point, dim3(512), dim3(256), 0, stream,
                     pv, feat, A1, ab1, B1, bb1, ob1, ob2, c0,
                     (const uint4*)aep, (const uint4*)bep, (const uint4*)o1t, (const uint4*)o2p,
                     qe, ke, vv, out);
  hipLaunchKernelGGL(k_main, dim3(2048), dim3(256), 0, stream,
                     pv, qe, ke, vv, (const uint4*)gtp, (const uint4*)e2p, (const uint4*)d1p,
                     out);
}

// Round 5
// 118.685 us; speedup vs baseline: 1.3645x; 1.0130x over previous
//
#include <hip/hip_runtime.h>
#include <hip/hip_bf16.h>
#include <cstdint>
#include <cstddef>

// PointAttention: out = concat( diag_softmax(eps_mlp((q_i - k_j + pij)*s)) * v , features )
// Folding: AE=s*A2@E1, BE=s*B2@E1, G=s*D2@E1, c0=s*(ab2-bb2+db2)@E1+eb1 (folded into qe); eb2 drops out.
// Softmax: logits O(1) (scale applied pre-MLP) -> no max-sub; E2 panel pre-scaled by log2e -> exp2.
// NOTE: k_main needs ~150 live VGPR+AGPR; launch_bounds(256,3) -> no spill, 3 waves/SIMD.
//       (256,4) capped at 128 and spilled acc to scratch: FETCH 24->236MB, 115->141us. Do not re-try.

#define SCALE 0.08838834764831843f
#define LOG2E 1.4426950408889634f

typedef __bf16 bf16x8 __attribute__((ext_vector_type(8)));
typedef float f32x16 __attribute__((ext_vector_type(16)));

__device__ __forceinline__ ushort f2b(float f){
  __hip_bfloat16 h = __float2bfloat16(f);
  return __builtin_bit_cast(ushort, h);
}
__device__ __forceinline__ float b2f(uint32_t s){
  union { uint32_t u; float f; } x; x.u = s << 16; return x.f;
}
__device__ __forceinline__ float blo(uint32_t u){
  union { uint32_t x; float f; } v; v.x = u << 16; return v.f;
}
__device__ __forceinline__ float bhi(uint32_t u){
  union { uint32_t x; float f; } v; v.x = u & 0xffff0000u; return v.f;
}
__device__ __forceinline__ uint32_t pk2(float a, float b){
  union { __hip_bfloat162 h2; uint32_t u; } x;
  x.h2.x = __float2bfloat16(a); x.h2.y = __float2bfloat16(b);
  return x.u;
}
__device__ __forceinline__ f32x16 MFMA(uint4 a, uint4 b, f32x16 c){
  return __builtin_amdgcn_mfma_f32_32x32x16_bf16(
      __builtin_bit_cast(bf16x8, a), __builtin_bit_cast(bf16x8, b), c, 0, 0, 0);
}

// ---------------- Kernel P: weight folding + panelization ----------------
// panel[k_oct][x][e] = Mat[8*k_oct+e][x]  (bf16, conflict-free for frag ds_read_b128)
__global__ __launch_bounds__(256) void k_pre(
    const float* __restrict__ A2, const float* __restrict__ B2, const float* __restrict__ D2,
    const float* __restrict__ E1, const float* __restrict__ E2,
    const float* __restrict__ O1, const float* __restrict__ O2,
    const float* __restrict__ ab2, const float* __restrict__ bb2, const float* __restrict__ db2,
    const float* __restrict__ eb1,
    const float* __restrict__ D1, const float* __restrict__ db1,
    ushort* __restrict__ aep, ushort* __restrict__ bep, ushort* __restrict__ gtp,
    ushort* __restrict__ e2p, ushort* __restrict__ o2p, ushort* __restrict__ o1t,
    ushort* __restrict__ d1p, float* __restrict__ c0)
{
  const int bid = blockIdx.x, tid = threadIdx.x;
  if (bid < 192){                 // AE / BE / G = s*(W @ E1), panelized
    const float* W = (bid < 64) ? A2 : (bid < 128) ? B2 : D2;
    ushort* dst    = (bid < 64) ? aep : (bid < 128) ? bep : gtp;
    int flat = (bid & 63)*256 + tid;
    int co = flat >> 10, rem = flat & 1023, h = rem >> 3, i = rem & 7;
    int r = co*8 + i;
    float acc = 0.f;
    for (int t = 0; t < 128; ++t) acc = fmaf(W[r*128 + t], E1[t*128 + h], acc);
    dst[(co*128 + h)*8 + i] = f2b(acc * SCALE);
  } else if (bid < 256){          // E2 panel, pre-scaled by log2e (softmax via exp2)
    int flat = (bid - 192)*256 + tid;
    int co = flat >> 10, rem = flat & 1023, d = rem >> 3, i = rem & 7;
    e2p[(co*128 + d)*8 + i] = f2b(E2[(co*8 + i)*128 + d] * LOG2E);
  } else if (bid < 320){          // O2 panel
    int flat = (bid - 256)*256 + tid;
    int co = flat >> 10, rem = flat & 1023, d = rem >> 3, i = rem & 7;
    o2p[(co*128 + d)*8 + i] = f2b(O2[(co*8 + i)*128 + d]);
  } else if (bid < 352){          // O1^T panel (A-operand: rows=o, k=f)
    int flat = (bid - 320)*256 + tid;   // 8192 elems
    int fo = flat >> 10, rem = flat & 1023, o = rem >> 3, e = rem & 7;
    o1t[(fo*128 + o)*8 + e] = f2b(O1[(fo*8 + e)*128 + o]);
  } else if (bid < 360){          // D1 A-frag panel: [2 koct][128 cd][8]
    int flat = (bid - 352)*256 + tid;   // 2048 elems
    int koct = flat >> 10, cd = (flat >> 3) & 127, e = flat & 7;
    float val = 0.f;
    if (koct == 0){
      if (e < 3) val = D1[e*128 + cd];
      else if (e == 3) val = db1[cd];
    }
    d1p[flat] = f2b(val);
  } else {
    if (tid < 128){
      float acc = 0.f;
      for (int t = 0; t < 128; ++t) acc = fmaf(ab2[t] - bb2[t] + db2[t], E1[t*128 + tid], acc);
      c0[tid] = acc * SCALE + eb1[tid];
    }
  }
}

// ---------------- Kernel Q: per-point qe/ke/v + features passthrough ----------------
__device__ __forceinline__ void gemm64x128(const ushort (*sa)[64][8], const ushort (*sw)[128][8],
                                           int w, int l31, int hl, int p0,
                                           const float* __restrict__ bias,
                                           ushort* __restrict__ dst)
{
  const int rw = w >> 1, ctb = (w & 1) * 2;
  f32x16 acc0, acc1;
#pragma unroll
  for (int r = 0; r < 16; ++r){ acc0[r] = 0.f; acc1[r] = 0.f; }
#pragma unroll
  for (int kk = 0; kk < 8; ++kk){
    uint4 a  = *(const uint4*)&sa[2*kk + hl][32*rw + l31][0];
    uint4 b0 = *(const uint4*)&sw[2*kk + hl][32*ctb + l31][0];
    uint4 b1 = *(const uint4*)&sw[2*kk + hl][32*(ctb+1) + l31][0];
    acc0 = MFMA(a, b0, acc0);
    acc1 = MFMA(a, b1, acc1);
  }
#pragma unroll
  for (int t = 0; t < 2; ++t){
    const f32x16 acc = t ? acc1 : acc0;
    const int d = 32*(ctb + t) + l31;
    const float bv = bias ? bias[d] : 0.f;
#pragma unroll
    for (int r = 0; r < 16; ++r){
      int row = 32*rw + (r & 3) + 8*(r >> 2) + 4*hl;
      dst[(size_t)(p0 + row)*128 + d] = f2b(acc[r] + bv);
    }
  }
}

__global__ __launch_bounds__(256, 2) void k_point(
    const float* __restrict__ pv, const float* __restrict__ feat,
    const float* __restrict__ A1, const float* __restrict__ ab1,
    const float* __restrict__ B1, const float* __restrict__ bb1,
    const float* __restrict__ ob1, const float* __restrict__ ob2,
    const float* __restrict__ c0,
    const uint4* __restrict__ aep, const uint4* __restrict__ bep,
    const uint4* __restrict__ o1t, const uint4* __restrict__ o2p,
    ushort* __restrict__ qe_ws, ushort* __restrict__ ke_ws, ushort* __restrict__ v_ws,
    float* __restrict__ out)
{
  __shared__ ushort sW[16][128][8];   // 32 KB weight panel
  __shared__ ushort sA[16][64][8];    // 16 KB activation panel
  __shared__ ushort sF[8][64][8];     // 8 KB  feature panel
  __shared__ float  sLw[3][128];
  __shared__ float  sLb[128];
  __shared__ float  sLb2[128];

  const int tid = threadIdx.x;
  const int p0  = blockIdx.x * 64;
  const int w = tid >> 6, lane = tid & 63, l31 = lane & 31, hl = lane >> 5;

  // exact f32 features passthrough: out[:,:,128:192]
  for (int idx = tid; idx < 64*16; idx += 256){
    int p = idx >> 4, k4 = idx & 15;
    float4 f = ((const float4*)(feat + (size_t)(p0 + p)*64))[k4];
    ((float4*)(out + (size_t)(p0 + p)*192 + 128))[k4] = f;
  }

  // ---- phase A: ha = relu(xyz@A1+ab1); qe = ha@AE + c0 ----
  for (int idx = tid; idx < 2048; idx += 256) ((uint4*)sW)[idx] = aep[idx];
  for (int idx = tid; idx < 384; idx += 256) ((float*)sLw)[idx] = A1[idx];
  if (tid < 128) sLb[tid] = ab1[tid];
  __syncthreads();
  {
    int p = tid & 63, ob = tid >> 6;
    float x0 = pv[(size_t)(p0+p)*3+0], x1 = pv[(size_t)(p0+p)*3+1], x2 = pv[(size_t)(p0+p)*3+2];
#pragma unroll
    for (int it = 0; it < 4; ++it){
      int oct = ob + 4*it;
      float h[8];
#pragma unroll
      for (int e = 0; e < 8; ++e){
        int cd = oct*8 + e;
        float t = fmaf(x0, sLw[0][cd], fmaf(x1, sLw[1][cd], fmaf(x2, sLw[2][cd], sLb[cd])));
        h[e] = fmaxf(t, 0.f);
      }
      uint4 u; u.x = pk2(h[0],h[1]); u.y = pk2(h[2],h[3]); u.z = pk2(h[4],h[5]); u.w = pk2(h[6],h[7]);
      *(uint4*)&sA[oct][p][0] = u;
    }
  }
  __syncthreads();
  gemm64x128(sA, sW, w, l31, hl, p0, c0, qe_ws);
  __syncthreads();

  // ---- phase B: ke = hb@BE ----
  for (int idx = tid; idx < 2048; idx += 256) ((uint4*)sW)[idx] = bep[idx];
  for (int idx = tid; idx < 384; idx += 256) ((float*)sLw)[idx] = B1[idx];
  if (tid < 128) sLb[tid] = bb1[tid];
  __syncthreads();
  {
    int p = tid & 63, ob = tid >> 6;
    float x0 = pv[(size_t)(p0+p)*3+0], x1 = pv[(size_t)(p0+p)*3+1], x2 = pv[(size_t)(p0+p)*3+2];
#pragma unroll
    for (int it = 0; it < 4; ++it){
      int oct = ob + 4*it;
      float h[8];
#pragma unroll
      for (int e = 0; e < 8; ++e){
        int cd = oct*8 + e;
        float t = fmaf(x0, sLw[0][cd], fmaf(x1, sLw[1][cd], fmaf(x2, sLw[2][cd], sLb[cd])));
        h[e] = fmaxf(t, 0.f);
      }
      uint4 u; u.x = pk2(h[0],h[1]); u.y = pk2(h[2],h[3]); u.z = pk2(h[4],h[5]); u.w = pk2(h[6],h[7]);
      *(uint4*)&sA[oct][p][0] = u;
    }
  }
  __syncthreads();
  gemm64x128(sA, sW, w, l31, hl, p0, nullptr, ke_ws);
  __syncthreads();

  // ---- phase C: ho^T = relu(O1^T @ feat^T + ob1) ----
  for (int idx = tid; idx < 512; idx += 256){
    int p = idx & 63, fo = idx >> 6;
    const float* fp = feat + (size_t)(p0 + p)*64 + 8*fo;
    float4 f0 = ((const float4*)fp)[0], f1 = ((const float4*)fp)[1];
    uint4 u; u.x = pk2(f0.x,f0.y); u.y = pk2(f0.z,f0.w); u.z = pk2(f1.x,f1.y); u.w = pk2(f1.z,f1.w);
    *(uint4*)&sF[fo][p][0] = u;
  }
  for (int idx = tid; idx < 1024; idx += 256) ((uint4*)sW)[idx] = o1t[idx];
  if (tid < 128) sLb[tid] = ob1[tid];
  __syncthreads();
  {
    f32x16 acc0, acc1;
#pragma unroll
    for (int r = 0; r < 16; ++r){ acc0[r] = 0.f; acc1[r] = 0.f; }
#pragma unroll
    for (int kk = 0; kk < 4; ++kk){
      uint4 a  = *(const uint4*)&sW[2*kk + hl][32*w + l31][0];
      uint4 b0 = *(const uint4*)&sF[2*kk + hl][l31][0];
      uint4 b1 = *(const uint4*)&sF[2*kk + hl][32 + l31][0];
      acc0 = MFMA(a, b0, acc0);
      acc1 = MFMA(a, b1, acc1);
    }
#pragma unroll
    for (int t = 0; t < 2; ++t){
      const f32x16 acc = t ? acc1 : acc0;
      const int pt = 32*t + l31;
#pragma unroll
      for (int q = 0; q < 4; ++q){
        int o0 = 32*w + 8*q + 4*hl;
        float z0 = fmaxf(acc[4*q+0] + sLb[o0+0], 0.f);
        float z1 = fmaxf(acc[4*q+1] + sLb[o0+1], 0.f);
        float z2 = fmaxf(acc[4*q+2] + sLb[o0+2], 0.f);
        float z3 = fmaxf(acc[4*q+3] + sLb[o0+3], 0.f);
        uint2 u; u.x = pk2(z0, z1); u.y = pk2(z2, z3);
        *(uint2*)&sA[4*w + q][pt][4*hl] = u;
      }
    }
  }
  __syncthreads();

  // ---- phase D: v = ho @ O2 + ob2 ----
  for (int idx = tid; idx < 2048; idx += 256) ((uint4*)sW)[idx] = o2p[idx];
  if (tid < 128) sLb2[tid] = ob2[tid];
  __syncthreads();
  {
    const int rw = w >> 1, ctb = (w & 1) * 2;
    f32x16 acc0, acc1;
#pragma unroll
    for (int r = 0; r < 16; ++r){ acc0[r] = 0.f; acc1[r] = 0.f; }
#pragma unroll
    for (int kk = 0; kk < 8; ++kk){
      uint4 a  = *(const uint4*)&sA[2*kk + hl][32*rw + l31][0];
      uint4 b0 = *(const uint4*)&sW[2*kk + hl][32*ctb + l31][0];
      uint4 b1 = *(const uint4*)&sW[2*kk + hl][32*(ctb+1) + l31][0];
      acc0 = MFMA(a, b0, acc0);
      acc1 = MFMA(a, b1, acc1);
    }
#pragma unroll
    for (int t = 0; t < 2; ++t){
      const f32x16 acc = t ? acc1 : acc0;
      const int d = 32*(ctb + t) + l31;
      const float bias = sLb2[d];
#pragma unroll
      for (int r = 0; r < 16; ++r){
        int row = 32*rw + (r & 3) + 8*(r >> 2) + 4*hl;
        v_ws[(size_t)(p0 + row)*128 + d] = f2b(acc[r] + bias);
      }
    }
  }
}

// ---------------- Kernel M: per-voxel attention core (half-voxel per block) ----------------
__global__ __launch_bounds__(256, 3) void k_main(
    const float* __restrict__ pv,
    const ushort* __restrict__ qe_ws, const ushort* __restrict__ ke_ws, const ushort* __restrict__ v_ws,
    const uint4* __restrict__ gtp, const uint4* __restrict__ e2p, const uint4* __restrict__ d1p,
    float* __restrict__ out)
{
  __shared__ ushort sHDE[16][128][8];  // 32 KB: HD panel, then HE panel (same buffer)
  __shared__ float  sQE[16][128];      // 8 KB: (qe + c0) f32 rows for this half-voxel
  __shared__ float  sXYZ[32][3];       // 384 B

  const int tid = threadIdx.x;
  const int b   = blockIdx.x >> 1;
  const int ch0 = (blockIdx.x & 1) * 4;   // chunks ch0..ch0+3 (rows i = 4*ch0 .. 4*ch0+15)
  const int w = tid >> 6, lane = tid & 63, l31 = lane & 31, hl = lane >> 5;

  for (int idx = tid; idx < 96; idx += 256) ((float*)sXYZ)[idx] = pv[(size_t)b*96 + idx];
  // this half-voxel's 16 qe rows (c0 already folded in k_point), bf16 -> f32
  for (int idx = tid; idx < 512; idx += 256){
    int il = idx >> 5, sl = idx & 31;
    uint2 qu = ((const uint2*)qe_ws)[(size_t)(b*32 + 4*ch0 + il)*32 + sl];
    float4 o; o.x = blo(qu.x); o.y = bhi(qu.x); o.z = blo(qu.y); o.w = bhi(qu.y);
    ((float4*)&sQE[il][0])[sl] = o;
  }

  // per-thread constants: ke[j=l31][h-slice] (16 f32), weight fragments
  float kreg[16];
  {
    const ushort* kp = ke_ws + (size_t)(b*32 + l31)*128 + 32*w + 4*hl;
#pragma unroll
    for (int q = 0; q < 4; ++q){
      uint2 ku = *(const uint2*)(kp + 8*q);
      kreg[4*q+0] = blo(ku.x); kreg[4*q+1] = bhi(ku.x);
      kreg[4*q+2] = blo(ku.y); kreg[4*q+3] = bhi(ku.y);
    }
  }
  uint4 wG[8], wE[8];
#pragma unroll
  for (int kk = 0; kk < 8; ++kk){
    wG[kk] = gtp[(2*kk + hl)*128 + 32*w + l31];  // A-frag rows h = 32w..32w+31
    wE[kk] = e2p[(2*kk + hl)*128 + 32*w + l31];  // B-frag cols d = 32w..32w+31 (pre-scaled log2e)
  }
  uint4 wD = d1p[hl*128 + 32*w + l31];           // A-frag rows cd = 32w..32w+31, K=4 padded

  f32x16 ZERO;
#pragma unroll
  for (int r = 0; r < 16; ++r) ZERO[r] = 0.f;
  __syncthreads();

  const float xj0 = sXYZ[l31][0], xj1 = sXYZ[l31][1], xj2 = sXYZ[l31][2];

#pragma unroll
  for (int cc = 0; cc < 4; ++cc){
    const int c = ch0 + cc;

    // ---- HD via MFMA: HD^T[cd][p] = relu([D1;db1]^T @ [dxyz;1]) ----
    f32x16 accD[4];
#pragma unroll
    for (int ct = 0; ct < 4; ++ct){
      const int i = 4*c + ct;
      float dx = fabsf(sXYZ[i][0] - xj0);
      float dy = fabsf(sXYZ[i][1] - xj1);
      float dz = fabsf(sXYZ[i][2] - xj2);
      uint4 bD; bD.x = pk2(dx, dy); bD.y = pk2(dz, 1.0f); bD.z = 0u; bD.w = 0u;
      accD[ct] = MFMA(wD, bD, ZERO);
    }
#pragma unroll
    for (int ct = 0; ct < 4; ++ct){
#pragma unroll
      for (int q = 0; q < 4; ++q){
        uint2 o;
        o.x = pk2(fmaxf(accD[ct][4*q+0],0.f), fmaxf(accD[ct][4*q+1],0.f));
        o.y = pk2(fmaxf(accD[ct][4*q+2],0.f), fmaxf(accD[ct][4*q+3],0.f));
        *(uint2*)&sHDE[4*w + q][32*ct + l31][4*hl] = o;
      }
    }
    __syncthreads();

    // ---- GEMM1: HE^T[h][p] = G^T @ HD^T, C-in = qe_i(+c0) - ke_j ----
    f32x16 acc1[4];
#pragma unroll
    for (int ct = 0; ct < 4; ++ct){
      const int il = 4*cc + ct;
#pragma unroll
      for (int q = 0; q < 4; ++q){
        float4 qv = *(const float4*)&sQE[il][32*w + 4*hl + 8*q];
        acc1[ct][4*q+0] = qv.x - kreg[4*q+0];
        acc1[ct][4*q+1] = qv.y - kreg[4*q+1];
        acc1[ct][4*q+2] = qv.z - kreg[4*q+2];
        acc1[ct][4*q+3] = qv.w - kreg[4*q+3];
      }
    }
#pragma unroll
    for (int kk = 0; kk < 8; ++kk){
      uint4 a = wG[kk];
#pragma unroll
      for (int ct = 0; ct < 4; ++ct){
        uint4 bu = *(const uint4*)&sHDE[2*kk + hl][32*ct + l31][0];
        acc1[ct] = MFMA(a, bu, acc1[ct]);
      }
    }
    __syncthreads();   // done reading HD panel

    // ---- relu -> HE panel (overwrite same LDS) ----
#pragma unroll
    for (int ct = 0; ct < 4; ++ct){
#pragma unroll
      for (int q = 0; q < 4; ++q){
        uint2 o;
        o.x = pk2(fmaxf(acc1[ct][4*q+0],0.f), fmaxf(acc1[ct][4*q+1],0.f));
        o.y = pk2(fmaxf(acc1[ct][4*q+2],0.f), fmaxf(acc1[ct][4*q+3],0.f));
        *(uint2*)&sHDE[4*w + q][32*ct + l31][4*hl] = o;
      }
    }
    __syncthreads();

    // ---- v prefetch (hides under GEMM2) ----
    float vv[4];
#pragma unroll
    for (int rt = 0; rt < 4; ++rt)
      vv[rt] = b2f((uint32_t)v_ws[(size_t)(b*32 + 4*c + rt)*128 + 32*w + l31]);

    // ---- GEMM2: W[j][d]*log2e = HE @ (E2*log2e)  (eb2 softmax-invariant) ----
    f32x16 acc2[4];
#pragma unroll
    for (int kk = 0; kk < 8; ++kk){
      uint4 bfrag = wE[kk];
#pragma unroll
      for (int rt = 0; rt < 4; ++rt){
        uint4 au = *(const uint4*)&sHDE[2*kk + hl][32*rt + l31][0];
        acc2[rt] = MFMA(au, bfrag, kk ? acc2[rt] : ZERO);
      }
    }
    __syncthreads();   // GEMM2 LDS reads drained; next chunk's HD may overwrite panel

    // ---- softmax over j per (i,d) via exp2, no max-sub; diag numerator; res = wii*v ----
    const int g = (c >> 1) & 3;     // diag register group (static-index select)
    const int hls = c & 1;          // diag hl half
#pragma unroll
    for (int rt = 0; rt < 4; ++rt){
      float e[16];
#pragma unroll
      for (int r = 0; r < 16; ++r) e[r] = __builtin_amdgcn_exp2f(acc2[rt][r]);
      float s01 = e[0]+e[1],   s23 = e[2]+e[3],   s45 = e[4]+e[5],   s67 = e[6]+e[7];
      float s89 = e[8]+e[9],   sab = e[10]+e[11], scd = e[12]+e[13], sef = e[14]+e[15];
      float s = ((s01+s23)+(s45+s67)) + ((s89+sab)+(scd+sef));
      s += __shfl_xor(s, 32);
      float num = (g == 0) ? e[rt] : (g == 1) ? e[rt+4] : (g == 2) ? e[rt+8] : e[rt+12];
      if (hl == hls){
        out[(size_t)(b*32 + 4*c + rt)*192 + 32*w + l31] = num * __builtin_amdgcn_rcpf(s) * vv[rt];
      }
    }
  }
}

// ---------------- launch ----------------
static constexpr size_t OFF_AEP = 0;
static constexpr size_t OFF_BEP = 32768;
static constexpr size_t OFF_GTP = 65536;
static constexpr size_t OFF_E2P = 98304;
static constexpr size_t OFF_O1T = 131072;
static constexpr size_t OFF_O2P = 147456;
static constexpr size_t OFF_C0  = 180224;
static constexpr size_t OFF_D1P = 180736;
static constexpr size_t OFF_QE  = 184832;
static constexpr size_t OFF_KE  = OFF_QE + (size_t)32768*128*2;
static constexpr size_t OFF_V   = OFF_KE + (size_t)32768*128*2;

extern "C" void kernel_launch(void* const* d_in, const int* in_sizes, int n_in,
                              void* d_out, int out_size, void* d_ws, size_t ws_size,
                              hipStream_t stream)
{
  (void)in_sizes; (void)n_in; (void)out_size; (void)ws_size;
  const float* pv   = (const float*)d_in[0];
  const float* feat = (const float*)d_in[1];
  const float* A1 = (const float*)d_in[2];  const float* ab1 = (const float*)d_in[3];
  const float* A2 = (const float*)d_in[4];  const float* ab2 = (const float*)d_in[5];
  const float* B1 = (const float*)d_in[6];  const float* bb1 = (const float*)d_in[7];
  const float* B2 = (const float*)d_in[8];  const float* bb2 = (const float*)d_in[9];
  const float* D1 = (const float*)d_in[10]; const float* db1 = (const float*)d_in[11];
  const float* D2 = (const float*)d_in[12]; const float* db2 = (const float*)d_in[13];
  const float* E1 = (const float*)d_in[14]; const float* eb1 = (const float*)d_in[15];
  const float* E2 = (const float*)d_in[16]; /* d_in[17] = eb2 unused (softmax-invariant) */
  const float* O1 = (const float*)d_in[18]; const float* ob1 = (const float*)d_in[19];
  const float* O2 = (const float*)d_in[20]; const float* ob2 = (const float*)d_in[21];

  char* ws = (char*)d_ws;
  ushort* aep = (ushort*)(ws + OFF_AEP);
  ushort* bep = (ushort*)(ws + OFF_BEP);
  ushort* gtp = (ushort*)(ws + OFF_GTP);
  ushort* e2p = (ushort*)(ws + OFF_E2P);
  ushort* o1t = (ushort*)(ws + OFF_O1T);
  ushort* o2p = (ushort*)(ws + OFF_O2P);
  float*  c0  = (float*)(ws + OFF_C0);
  ushort* d1p = (ushort*)(ws + OFF_D1P);
  ushort* qe  = (ushort*)(ws + OFF_QE);
  ushort* ke  = (ushort*)(ws + OFF_KE);
  ushort* vv  = (ushort*)(ws + OFF_V);
  float* out = (float*)d_out;

  hipLaunchKernelGGL(k_pre, dim3(361), dim3(256), 0, stream,
                     A2, B2, D2, E1, E2, O1, O2, ab2, bb2, db2, eb1, D1, db1,
                     aep, bep, gtp, e2p, o2p, o1t, d1p, c0);
  hipLaunchKernelGGL(k_point, dim3(512), dim3(256), 0, stream,
                     pv, feat, A1, ab1, B1, bb1, ob1, ob2, c0,
                     (const uint4*)aep, (const uint4*)bep, (const uint4*)o1t, (const uint4*)o2p,
                     qe, ke, vv, out);
  hipLaunchKernelGGL(k_main, dim3(2048), dim3(256), 0, stream,
                     pv, qe, ke, vv, (const uint4*)gtp, (const uint4*)e2p, (const uint4*)d1p,
                     out);
}